// Round 4
// baseline (581.016 us; speedup 1.0000x reference)
//
#include <hip/hip_runtime.h>
#include <stdint.h>
#include <stddef.h>

// out[65536,1024] = X . W0^T + b0 (fp32 in/out) via bf16 MFMA.
// R6: eliminate the A reg-staging complex (the invariant ~1.5K cyc/phase lump:
// vmcnt-wait -> cvt -> ds_write -> lgkm-drain, exposed in lockstep every tile).
// X is pre-converted to bf16 in the workspace by a BW-bound pass (~67 us);
// the GEMM then stages BOTH operands via global_load_lds with the swizzle
// folded into per-lane global addresses (B's proven pattern, reused for A).
// m201-style: one half-tile staged per phase, counted vmcnt(4)/vmcnt(6),
// never drained to 0 mid-loop. Fallback to the R5 kernel if ws too small.

#define BATCH   65536
#define HIDDEN  1024
#define BM      256
#define BN      256
#define BK      64
#define NT      (HIDDEN / BK)   // 16 K-tiles
#define X_ELEMS ((size_t)BATCH * HIDDEN)

typedef __bf16 bf16;
typedef __attribute__((ext_vector_type(8))) __bf16 bf16x8;
typedef __attribute__((ext_vector_type(4))) __bf16 bf16x4;
typedef __attribute__((ext_vector_type(4))) float  f32x4;

#define MEMFENCE  asm volatile("" ::: "memory")
#define WAITVM(N) asm volatile("s_waitcnt vmcnt(" #N ")" ::: "memory")
#define LGKM0     asm volatile("s_waitcnt lgkmcnt(0)" ::: "memory")
#define BARRIER() do { MEMFENCE; __builtin_amdgcn_s_barrier(); MEMFENCE; } while (0)

__device__ __forceinline__ void async_ld16(const bf16* g, bf16* l) {
    __builtin_amdgcn_global_load_lds(
        (const __attribute__((address_space(1))) uint32_t*)g,
        (__attribute__((address_space(3))) uint32_t*)l,
        16, 0, 0);
}

__device__ __forceinline__ bf16x4 cvt4(f32x4 a) {
    bf16x4 r;
    r[0] = (bf16)a[0]; r[1] = (bf16)a[1]; r[2] = (bf16)a[2]; r[3] = (bf16)a[3];
    return r;
}

__device__ __forceinline__ bf16x8 cvt8(f32x4 a, f32x4 b) {
    bf16x8 r;
    r[0] = (bf16)a[0]; r[1] = (bf16)a[1]; r[2] = (bf16)a[2]; r[3] = (bf16)a[3];
    r[4] = (bf16)b[0]; r[5] = (bf16)b[1]; r[6] = (bf16)b[2]; r[7] = (bf16)b[3];
    return r;
}

__global__ void convert_w_kernel(const float* __restrict__ W, bf16* __restrict__ Wb) {
    int i = (blockIdx.x * 256 + threadIdx.x) * 4;
    f32x4 v = *(const f32x4*)(W + i);
    *(bf16x4*)(Wb + i) = cvt4(v);
}

__global__ __launch_bounds__(256)
void convert_x_kernel(const float* __restrict__ X, bf16* __restrict__ Xb) {
    size_t i = ((size_t)blockIdx.x * 256 + threadIdx.x) * 8;
    const size_t stride = (size_t)gridDim.x * 256 * 8;
    for (; i < X_ELEMS; i += stride) {
        f32x4 a = *(const f32x4*)(X + i);
        f32x4 b = *(const f32x4*)(X + i + 4);
        *(bf16x8*)(Xb + i) = cvt8(a, b);
    }
}

// LDS byte map (dynamic, 128 KiB):
//   A: buf*32768 + row*128 + slot*16           (row 0..255, slot 0..7)
//   B: 65536 + buf*32768 + row*128 + slot*16
// Content invariant: LDS (row r, slot s) holds global granule s ^ (r&7).
// A half h = rows with bit6 == h (read ph0/ph2); B half h = bit5 (ph0/ph1).

#define READ_A(BUF, MH) do {                                                  \
    const char* _ab = smem + (BUF)*32768 + arr + (MH)*8192;                   \
    aF[0][0] = *(const bf16x8*)(_ab + 0*2048 + fsl0);                         \
    aF[0][1] = *(const bf16x8*)(_ab + 0*2048 + fsl1);                         \
    aF[1][0] = *(const bf16x8*)(_ab + 1*2048 + fsl0);                         \
    aF[1][1] = *(const bf16x8*)(_ab + 1*2048 + fsl1);                         \
    aF[2][0] = *(const bf16x8*)(_ab + 2*2048 + fsl0);                         \
    aF[2][1] = *(const bf16x8*)(_ab + 2*2048 + fsl1);                         \
    aF[3][0] = *(const bf16x8*)(_ab + 3*2048 + fsl0);                         \
    aF[3][1] = *(const bf16x8*)(_ab + 3*2048 + fsl1);                         \
} while (0)

#define READ_B(BUF, NH) do {                                                  \
    const char* _bb = smem + 65536 + (BUF)*32768 + brr + (NH)*4096;           \
    bF[NH][0][0] = *(const bf16x8*)(_bb + 0*2048 + fsl0);                     \
    bF[NH][0][1] = *(const bf16x8*)(_bb + 0*2048 + fsl1);                     \
    bF[NH][1][0] = *(const bf16x8*)(_bb + 1*2048 + fsl0);                     \
    bF[NH][1][1] = *(const bf16x8*)(_bb + 1*2048 + fsl1);                     \
} while (0)

#define MM(MH, NH, MI, NI, KS)                                                \
    acc[(MH)*4+(MI)][(NH)*2+(NI)] = __builtin_amdgcn_mfma_f32_16x16x32_bf16(  \
        aF[(MI)][(KS)], bF[(NH)][(NI)][(KS)], acc[(MH)*4+(MI)][(NH)*2+(NI)], 0, 0, 0)

#define MFMA_Q(MH, NH) do {                                                   \
    __builtin_amdgcn_s_setprio(1);                                            \
    MM(MH,NH,0,0,0); MM(MH,NH,1,0,0); MM(MH,NH,2,0,0); MM(MH,NH,3,0,0);       \
    MM(MH,NH,0,1,0); MM(MH,NH,1,1,0); MM(MH,NH,2,1,0); MM(MH,NH,3,1,0);       \
    MM(MH,NH,0,0,1); MM(MH,NH,1,0,1); MM(MH,NH,2,0,1); MM(MH,NH,3,0,1);       \
    MM(MH,NH,0,1,1); MM(MH,NH,1,1,1); MM(MH,NH,2,1,1); MM(MH,NH,3,1,1);       \
    __builtin_amdgcn_s_setprio(0);                                            \
} while (0)

// B stage: 2 x global_load_lds per half (2 vmcnt ops), linear LDS dst,
// swizzle folded into per-lane global source.
#define ISSUE_SB(DBUF, KT, H) do {                                            \
    const bf16* _g0 = bSrc0 + (size_t)(H)*32*HIDDEN + (KT)*BK;                \
    const bf16* _g1 = bSrc1 + (size_t)(H)*32*HIDDEN + (KT)*BK;                \
    bf16* _d0 = (bf16*)(smem + 65536 + (DBUF)*32768 + (brb0 + (H)*32)*128);   \
    bf16* _d1 = (bf16*)(smem + 65536 + (DBUF)*32768 + (brb1 + (H)*32)*128);   \
    async_ld16(_g0, _d0);                                                     \
    async_ld16(_g1, _d1);                                                     \
} while (0)

// A stage (R6): 2 x global_load_lds per half (2 vmcnt ops), same pattern.
// Wave w covers rows {H*64 + w*8 ..+7} and {128 + H*64 + w*8 ..+7}.
#define ISSUE_SA6(DBUF, KT, H) do {                                           \
    const bf16* _g0 = aSrc6 + (size_t)((H)*64 + wave*8) * HIDDEN + (KT)*BK;   \
    const bf16* _g1 = _g0 + (size_t)128 * HIDDEN;                             \
    bf16* _d0 = (bf16*)(smem + (DBUF)*32768 + ((H)*64 + wave*8) * 128);       \
    bf16* _d1 = _d0 + 128 * 64;                                              \
    async_ld16(_g0, _d0);                                                     \
    async_ld16(_g1, _d1);                                                     \
} while (0)

// R6 K-tile = 4 phases. Per-wave vm issue order (2 ops each, steady state):
//   SA0(t+1)@ph3(t-1), SB0(t+1)@ph0(t), SA1(t+1)@ph1(t), SB1(t+1)@ph2(t),
//   SA0(t+2)@ph3(t), ...
// Waits:
//   end-ph0(t) WAITVM(4): SB1(t) done (newer: SA0(t+1),SB0(t+1)=4); also
//                         drains SA1(t) for ph2. >=2-phase slack.
//   end-ph3(t) WAITVM(6): SA0(t+1)+SB0(t+1) done (newer: SA1,SB1,SA0(t+2)=6).
//   Tail: t=NT-2 end-ph3 -> WAITVM(4); t=NT-1 end-ph0 -> WAITVM(0).
#define TILE_STEP6(BUF, OBUF, T) do {                                         \
    /* ---- phase 0: Q(M0,N0) ---- */                                         \
    READ_A(BUF, 0); READ_B(BUF, 0);                                           \
    MEMFENCE;                                                                 \
    if ((T) + 1 < NT) { ISSUE_SB(OBUF, (T)+1, 0); }                           \
    MEMFENCE;                                                                 \
    BARRIER();                                                                \
    MFMA_Q(0, 0);                                                             \
    if ((T) + 1 < NT) { WAITVM(4); } else { WAITVM(0); }                      \
    BARRIER();                                                                \
    /* ---- phase 1: Q(M0,N1) ---- */                                         \
    READ_B(BUF, 1);                                                           \
    MEMFENCE;                                                                 \
    if ((T) + 1 < NT) { ISSUE_SA6(OBUF, (T)+1, 1); }                          \
    MEMFENCE;                                                                 \
    BARRIER();                                                                \
    MFMA_Q(0, 1);                                                             \
    BARRIER();                                                                \
    /* ---- phase 2: Q(M1,N0) ---- */                                         \
    READ_A(BUF, 1);                                                           \
    MEMFENCE;                                                                 \
    if ((T) + 1 < NT) { ISSUE_SB(OBUF, (T)+1, 1); }                           \
    MEMFENCE;                                                                 \
    BARRIER();                                                                \
    MFMA_Q(1, 0);                                                             \
    BARRIER();                                                                \
    /* ---- phase 3: Q(M1,N1) ---- */                                         \
    MEMFENCE;                                                                 \
    if ((T) + 2 < NT) { ISSUE_SA6(BUF, (T)+2, 0); }                           \
    MEMFENCE;                                                                 \
    MFMA_Q(1, 1);                                                             \
    if ((T) + 2 < NT)      { WAITVM(6); }                                     \
    else if ((T) + 1 < NT) { WAITVM(4); }                                     \
    BARRIER();                                                                \
} while (0)

__global__ __launch_bounds__(512, 2)
void moa_gemm_kernel6(const bf16* __restrict__ Xb, const bf16* __restrict__ Wb,
                      const float* __restrict__ bias, float* __restrict__ out) {
    extern __shared__ __align__(16) char smem[];

    const int tid  = threadIdx.x;
    const int wave = tid >> 6;
    const int lane = tid & 63;

    // XCD-aware remap: contiguous 128-id chunk per XCD.
    const int wgid  = ((blockIdx.x & 7) << 7) | (blockIdx.x >> 3);
    const int tileM = (wgid >> 2) * BM;
    const int tileN = (wgid & 3) * BN;

    const int wr = wave >> 2;   // 0..1  (M)
    const int wc = wave & 3;    // 0..3  (N)

    // ---- A staging (gl_lds): lane l -> row +(l>>3), granule (l&7)^(l>>3) ----
    const bf16* aSrc6 = Xb + (size_t)(tileM + (lane >> 3)) * HIDDEN
                           + ((lane & 7) ^ (lane >> 3)) * 8;

    // ---- B staging: per (half,j) chunk of 8 rows x 8 slots ----
    const int bc0  = wave * 2;
    const int brb0 = ((bc0 >> 2) << 6) + ((bc0 & 3) << 3);
    const int brb1 = (((bc0 + 1) >> 2) << 6) + (((bc0 + 1) & 3) << 3);
    const int bg   = ((lane & 7) ^ (lane >> 3)) * 8;
    const bf16* bSrc0 = Wb + (size_t)(tileN + brb0 + (lane >> 3)) * HIDDEN + bg;
    const bf16* bSrc1 = Wb + (size_t)(tileN + brb1 + (lane >> 3)) * HIDDEN + bg;

    // ---- fragment read map (16x16x32), swizzled slots ----
    const int frow = lane & 15, fq = lane >> 4;
    const int fsl0 = ((fq)     ^ (lane & 7)) * 16;    // kstep 0
    const int fsl1 = ((4 + fq) ^ (lane & 7)) * 16;    // kstep 1
    const int arr  = (wr * 128 + frow) * 128;         // + mh*8192 + mi*2048
    const int brr  = (wc * 64  + frow) * 128;         // + nh*4096 + ni*2048

    f32x4 acc[8][4];
    #pragma unroll
    for (int i = 0; i < 8; ++i)
        #pragma unroll
        for (int j = 0; j < 4; ++j) acc[i][j] = f32x4{0.f, 0.f, 0.f, 0.f};

    bf16x8 aF[4][2];
    bf16x8 bF[2][2][2];

    // ---- prologue: tile0 all 4 halves -> buf0; SA0(1) -> buf1 ----
    MEMFENCE;
    ISSUE_SA6(0, 0, 0);
    ISSUE_SB(0, 0, 0);
    ISSUE_SA6(0, 0, 1);
    ISSUE_SB(0, 0, 1);
    ISSUE_SA6(1, 1, 0);
    MEMFENCE;
    WAITVM(6);                   // SA0(0)+SB0(0) done; 6 newer still in flight
    BARRIER();

    #pragma unroll 1
    for (int tp = 0; tp < NT / 2; ++tp) {
        const int t0 = 2 * tp;
        const int t1 = 2 * tp + 1;
        TILE_STEP6(0, 1, t0);
        TILE_STEP6(1, 0, t1);
    }

    // ---- epilogue: C/D layout col=lane&15, row=(lane>>4)*4+r ----
    const int orow0 = tileM + wr * 128 + ((lane >> 4) << 2);
    const int ocol0 = tileN + wc * 64 + (lane & 15);
    const float bv0 = bias[ocol0];
    const float bv1 = bias[ocol0 + 16];
    const float bv2 = bias[ocol0 + 32];
    const float bv3 = bias[ocol0 + 48];
    #pragma unroll
    for (int mi = 0; mi < 8; ++mi) {
        #pragma unroll
        for (int r = 0; r < 4; ++r) {
            float* op = out + (size_t)(orow0 + mi * 16 + r) * HIDDEN + ocol0;
            op[0]  = acc[mi][0][r] + bv0;
            op[16] = acc[mi][1][r] + bv1;
            op[32] = acc[mi][2][r] + bv2;
            op[48] = acc[mi][3][r] + bv3;
        }
    }
}

// ======================= R5 fallback (ws too small) ==========================

#define ISSUE_LA(LR, KT, H) do {                                              \
    const float* _s = aSrc + (size_t)(H)*64*HIDDEN + (KT)*BK;                 \
    LR[0] = *(const f32x4*)(_s);                                              \
    LR[1] = *(const f32x4*)(_s +  32*HIDDEN);                                 \
    LR[2] = *(const f32x4*)(_s + 128*HIDDEN);                                 \
    LR[3] = *(const f32x4*)(_s + 160*HIDDEN);                                 \
} while (0)

#define WRITE_A(LR, DBUF, H) do {                                             \
    char* _d = smem + (DBUF)*32768 + aw_byte + (H)*8192;                      \
    *(bf16x4*)(_d +     0) = cvt4(LR[0]);                                     \
    *(bf16x4*)(_d +  4096) = cvt4(LR[1]);                                     \
    *(bf16x4*)(_d + 16384) = cvt4(LR[2]);                                     \
    *(bf16x4*)(_d + 20480) = cvt4(LR[3]);                                     \
} while (0)

#define TILE_STEP5(BUF, OBUF, T) do {                                         \
    READ_A(BUF, 0); READ_B(BUF, 0);                                           \
    MEMFENCE;                                                                 \
    if ((T) < NT-1) { ISSUE_LA(la0, (T)+1, 0); }                              \
    MEMFENCE;                                                                 \
    BARRIER();                                                                \
    MFMA_Q(0, 0);                                                             \
    WRITE_A(la1, BUF, 1);                                                     \
    LGKM0;                                                                    \
    BARRIER();                                                                \
    READ_B(BUF, 1);                                                           \
    MEMFENCE;                                                                 \
    if ((T) < NT-1) { ISSUE_LA(la1, (T)+1, 1); }                              \
    MEMFENCE;                                                                 \
    BARRIER();                                                                \
    MFMA_Q(0, 1);                                                             \
    BARRIER();                                                                \
    READ_A(BUF, 1);                                                           \
    BARRIER();                                                                \
    MFMA_Q(1, 0);                                                             \
    BARRIER();                                                                \
    MFMA_Q(1, 1);                                                             \
    MEMFENCE;                                                                 \
    if ((T) + 2 < NT) { ISSUE_SB(BUF, (T)+2, 0); ISSUE_SB(BUF, (T)+2, 1); }   \
    MEMFENCE;                                                                 \
    if ((T) < NT-1) { WRITE_A(la0, OBUF, 0); }                                \
    if ((T) + 2 < NT)      { WAITVM(12); }                                    \
    else if ((T) + 1 < NT) { WAITVM(8); }                                     \
    LGKM0;                                                                    \
    BARRIER();                                                                \
} while (0)

__global__ __launch_bounds__(512, 2)
void moa_gemm_kernel5(const float* __restrict__ X, const bf16* __restrict__ Wb,
                      const float* __restrict__ bias, float* __restrict__ out) {
    extern __shared__ __align__(16) char smem[];

    const int tid  = threadIdx.x;
    const int wave = tid >> 6;
    const int lane = tid & 63;

    const int wgid  = ((blockIdx.x & 7) << 7) | (blockIdx.x >> 3);
    const int tileM = (wgid >> 2) * BM;
    const int tileN = (wgid & 3) * BN;

    const int wr = wave >> 2;
    const int wc = wave & 3;

    const float* aSrc = X + (size_t)(tileM + (tid >> 4)) * HIDDEN + (tid & 15) * 4;
    const int aw_byte = (tid >> 4) * 128
                      + ((((tid & 15) >> 1) ^ ((tid >> 4) & 7)) * 16)
                      + (tid & 1) * 8;

    const int bc0  = wave * 2;
    const int brb0 = ((bc0 >> 2) << 6) + ((bc0 & 3) << 3);
    const int brb1 = (((bc0 + 1) >> 2) << 6) + (((bc0 + 1) & 3) << 3);
    const int bg   = ((lane & 7) ^ (lane >> 3)) * 8;
    const bf16* bSrc0 = Wb + (size_t)(tileN + brb0 + (lane >> 3)) * HIDDEN + bg;
    const bf16* bSrc1 = Wb + (size_t)(tileN + brb1 + (lane >> 3)) * HIDDEN + bg;

    const int frow = lane & 15, fq = lane >> 4;
    const int fsl0 = ((fq)     ^ (lane & 7)) * 16;
    const int fsl1 = ((4 + fq) ^ (lane & 7)) * 16;
    const int arr  = (wr * 128 + frow) * 128;
    const int brr  = (wc * 64  + frow) * 128;

    f32x4 acc[8][4];
    #pragma unroll
    for (int i = 0; i < 8; ++i)
        #pragma unroll
        for (int j = 0; j < 4; ++j) acc[i][j] = f32x4{0.f, 0.f, 0.f, 0.f};

    bf16x8 aF[4][2];
    bf16x8 bF[2][2][2];
    f32x4  la0[4], la1[4];

    MEMFENCE;
    ISSUE_LA(la0, 0, 0);
    MEMFENCE;
    ISSUE_LA(la1, 0, 1);
    MEMFENCE;
    ISSUE_SB(0, 0, 0);
    ISSUE_SB(0, 0, 1);
    MEMFENCE;
    ISSUE_SB(1, 1, 0);
    ISSUE_SB(1, 1, 1);
    MEMFENCE;
    WRITE_A(la0, 0, 0);
    WRITE_A(la1, 0, 1);
    WAITVM(4);
    LGKM0;
    BARRIER();

    #pragma unroll 1
    for (int tp = 0; tp < NT / 2; ++tp) {
        const int t0 = 2 * tp;
        const int t1 = 2 * tp + 1;
        TILE_STEP5(0, 1, t0);
        TILE_STEP5(1, 0, t1);
    }

    const int orow0 = tileM + wr * 128 + ((lane >> 4) << 2);
    const int ocol0 = tileN + wc * 64 + (lane & 15);
    const float bv0 = bias[ocol0];
    const float bv1 = bias[ocol0 + 16];
    const float bv2 = bias[ocol0 + 32];
    const float bv3 = bias[ocol0 + 48];
    #pragma unroll
    for (int mi = 0; mi < 8; ++mi) {
        #pragma unroll
        for (int r = 0; r < 4; ++r) {
            float* op = out + (size_t)(orow0 + mi * 16 + r) * HIDDEN + ocol0;
            op[0]  = acc[mi][0][r] + bv0;
            op[16] = acc[mi][1][r] + bv1;
            op[32] = acc[mi][2][r] + bv2;
            op[48] = acc[mi][3][r] + bv3;
        }
    }
}

extern "C" void kernel_launch(void* const* d_in, const int* in_sizes, int n_in,
                              void* d_out, int out_size, void* d_ws, size_t ws_size,
                              hipStream_t stream) {
    const float* x  = (const float*)d_in[0];
    const float* W  = (const float*)d_in[2];   // [8,1024,1024]; adaptor 0 first
    const float* b  = (const float*)d_in[3];   // [8,1024]
    float* out      = (float*)d_out;

    hipFuncSetAttribute((const void*)moa_gemm_kernel6,
                        hipFuncAttributeMaxDynamicSharedMemorySize, 131072);
    hipFuncSetAttribute((const void*)moa_gemm_kernel5,
                        hipFuncAttributeMaxDynamicSharedMemorySize, 131072);

    const size_t xb_bytes = X_ELEMS * sizeof(bf16);                 // 134 MB
    const size_t wb_bytes = (size_t)HIDDEN * HIDDEN * sizeof(bf16); //   2 MB

    if (ws_size >= xb_bytes + wb_bytes) {
        bf16* Xb = (bf16*)d_ws;
        bf16* Wb = (bf16*)((char*)d_ws + xb_bytes);
        convert_x_kernel<<<dim3(2048), dim3(256), 0, stream>>>(x, Xb);
        convert_w_kernel<<<dim3(HIDDEN * HIDDEN / (256 * 4)), dim3(256), 0, stream>>>(W, Wb);
        moa_gemm_kernel6<<<dim3((BATCH / BM) * (HIDDEN / BN)), dim3(512), 131072, stream>>>(
            Xb, Wb, b, out);
    } else {
        bf16* Wb = (bf16*)d_ws;
        convert_w_kernel<<<dim3(HIDDEN * HIDDEN / (256 * 4)), dim3(256), 0, stream>>>(W, Wb);
        moa_gemm_kernel5<<<dim3((BATCH / BM) * (HIDDEN / BN)), dim3(512), 131072, stream>>>(
            x, Wb, b, out);
    }
}